// Round 9
// baseline (174.137 us; speedup 1.0000x reference)
//
#include <hip/hip_runtime.h>
#include <hip/hip_bf16.h>

typedef unsigned short u16;
typedef __attribute__((ext_vector_type(8))) short short8;
typedef __attribute__((ext_vector_type(4))) float floatx4;

#define MFMA_BF16 __builtin_amdgcn_mfma_f32_16x16x32_bf16

// RNE f32->bf16 via compiler cast (bit-identical to manual integer RNE).
__device__ __forceinline__ u16 f2bf(float f) {
    union { __hip_bfloat16 h; u16 u; } cv;
    cv.h = __float2bfloat16(f);
    return cv.u;
}
__device__ __forceinline__ float leaky(float x) { return x >= 0.f ? x : 0.01f * x; }

#define H1S 264  // 256 + 8 (h1 / h2 row stride)
#define RS 232   // 224 + 8 (SM raw stage stride)
#define XS 168   // 160 + 8 (PM x stage stride)
#define H3S 72   // 64 + 8  (SM h3 stride)

// out-region offsets (elements)
#define O1 917504
#define O2 946176
#define O3 974848
#define O4 1003520

// packed-weight ws offsets (u16 elements)
#define PW1   0        // pm_w1  16*5*512  = 40960
#define PW3   40960    // pm_w3  32*8*512  = 131072
#define PWM2  172032   // pm_wm2 1*16*512  = 8192
#define PSW2  180224   // sm_w2  16*7*512  = 57344
#define PSW3  237568   // sm_w3  16*8*512  = 65536
#define PSW5  303104   // sm_w5  4*8*512   = 16384
#define PSW6  319488   // sm_w6  1*2*512   = 1024
#define PTOTAL 320512  // u16 elements -> 641024 bytes
#define WS_NEEDED 641024
#define WS_BIG (641024 + 3670016)   // + sp f32 [65536*14]

// ===========================================================================
// Merged pack kernel: all 7 weights f32 row-major -> bf16 fragment-major.
// ===========================================================================
struct PackSeg { const float* W; int K, N, S, base, count; };
struct PackArgs { PackSeg seg[7]; };

__global__ __launch_bounds__(256) void pack_all(PackArgs pa, u16* __restrict__ P) {
    int u = blockIdx.x * 256 + threadIdx.x;
    if (u >= PTOTAL) return;
#pragma unroll
    for (int i = 0; i < 7; i++) {
        if (u >= pa.seg[i].base && u < pa.seg[i].base + pa.seg[i].count) {
            int v = u - pa.seg[i].base;
            int j = v & 7;
            int l = (v >> 3) & 63;
            int ts = v >> 9;
            int s = ts % pa.seg[i].S;
            int t = ts / pa.seg[i].S;
            int k = s * 32 + (l >> 4) * 8 + j;
            int n = t * 16 + (l & 15);
            P[u] = (k < pa.seg[i].K && n < pa.seg[i].N)
                       ? f2bf(pa.seg[i].W[k * pa.seg[i].N + n]) : (u16)0;
            return;
        }
    }
}

// ===========================================================================
// Merged MLP kernel, v8 (champion ~44us; geometry ledger closed: waves/CU
// 8->62us, 16->44us, 24(+Btraf)->52us; setprio null; serial-cost cuts null).
//   blocks 0..31    : sensor model (2048 unique rows) -> ez (out+O4)
//   blocks 32..1055 : process model, 2 batches each -> sp_ws
// ===========================================================================
__global__ __launch_bounds__(512, 4) void merged_mlp(
    const float* __restrict__ Rg, const float* __restrict__ Xg,
    const u16* __restrict__ Pk,
    const float* __restrict__ b1, const float* __restrict__ b3,
    const float* __restrict__ bm2,
    const float* __restrict__ b2, const float* __restrict__ sb3,
    const float* __restrict__ b5, const float* __restrict__ b6,
    float* __restrict__ ez_out,   // out + O4
    float* __restrict__ sp_ws)    // [65536*14]
{
    __shared__ __align__(16) u16 ldsH[64 * H1S];  // stage -> h2 -> h3/pacc
    __shared__ __align__(16) u16 ldsC[64 * H1S];  // h1 -> pacc/pacc2

    const int tid  = threadIdx.x;
    const int lane = tid & 63;
    const int wave = tid >> 6;    // 0..7
    const int q    = lane >> 4;
    const int n16  = lane & 15;

    if (blockIdx.x < 32) {
        // ---------------- sensor model path (64 rows) ----------------
        const u16* w2p = Pk + PSW2;
        const u16* w3p = Pk + PSW3;
        const u16* w5p = Pk + PSW5;
        const u16* w6p = Pk + PSW6;
        const int row0 = blockIdx.x * 64;

        // stage raw (f32 -> bf16), zero-pad 220 -> 224, into ldsH (stride RS)
        for (int idx = tid; idx < 64 * 56; idx += 512) {
            int r = idx / 56, c4 = idx - r * 56;
            float4 v = {0.f, 0.f, 0.f, 0.f};
            if (c4 < 55) v = *(const float4*)&Rg[(row0 + r) * 220 + c4 * 4];
            ushort4 pk;
            pk.x = f2bf(v.x); pk.y = f2bf(v.y); pk.z = f2bf(v.z); pk.w = f2bf(v.w);
            *(ushort4*)&ldsH[r * RS + c4 * 4] = pk;
        }
        __syncthreads();   // B1: stage visible

        // L1: 224K -> 256 ; reads ldsH, publishes h1 -> ldsC (ping-pong)
        {
            floatx4 zero = {0.f, 0.f, 0.f, 0.f};
            floatx4 acc1[4][2];
#pragma unroll
            for (int rt = 0; rt < 4; rt++)
#pragma unroll
                for (int ct = 0; ct < 2; ct++) acc1[rt][ct] = zero;
#pragma unroll
            for (int s = 0; s < 7; s++) {
                short8 a[4];
#pragma unroll
                for (int rt = 0; rt < 4; rt++)
                    a[rt] = *(const short8*)&ldsH[(rt * 16 + n16) * RS + s * 32 + q * 8];
#pragma unroll
                for (int ct = 0; ct < 2; ct++) {
                    int t = wave * 2 + ct;
                    short8 bf = *(const short8*)&w2p[((t * 7 + s) * 64 + lane) * 8];
#pragma unroll
                    for (int rt = 0; rt < 4; rt++)
                        acc1[rt][ct] = MFMA_BF16(a[rt], bf, acc1[rt][ct], 0, 0, 0);
                }
            }
#pragma unroll
            for (int ct = 0; ct < 2; ct++) {
                int col = (wave * 2 + ct) * 16 + n16;
                float bias = b2[col];
#pragma unroll
                for (int rt = 0; rt < 4; rt++)
#pragma unroll
                    for (int r = 0; r < 4; r++)
                        ldsC[(rt * 16 + q * 4 + r) * H1S + col] = f2bf(leaky(acc1[rt][ct][r] + bias));
            }
        }
        __syncthreads();   // B2: h1 visible (and all stage reads done)

        // L2: 256 -> 256; reads ldsC (h1), publishes h2 -> ldsH (stage dead)
        {
            floatx4 zero = {0.f, 0.f, 0.f, 0.f};
            floatx4 acc[4][2];
#pragma unroll
            for (int rt = 0; rt < 4; rt++)
#pragma unroll
                for (int ct = 0; ct < 2; ct++) acc[rt][ct] = zero;
#pragma unroll
            for (int s = 0; s < 8; s++) {
                short8 a[4];
#pragma unroll
                for (int rt = 0; rt < 4; rt++)
                    a[rt] = *(const short8*)&ldsC[(rt * 16 + n16) * H1S + s * 32 + q * 8];
#pragma unroll
                for (int ct = 0; ct < 2; ct++) {
                    int t = wave * 2 + ct;
                    short8 bf = *(const short8*)&w3p[((t * 8 + s) * 64 + lane) * 8];
#pragma unroll
                    for (int rt = 0; rt < 4; rt++)
                        acc[rt][ct] = MFMA_BF16(a[rt], bf, acc[rt][ct], 0, 0, 0);
                }
            }
#pragma unroll
            for (int ct = 0; ct < 2; ct++) {
                int cl = (wave * 2 + ct) * 16 + n16;
                float bias = sb3[cl];
#pragma unroll
                for (int rt = 0; rt < 4; rt++)
#pragma unroll
                    for (int r = 0; r < 4; r++)
                        ldsH[(rt * 16 + q * 4 + r) * H1S + cl] = f2bf(leaky(acc[rt][ct][r] + bias));
            }
        }
        __syncthreads();   // B3: h2 visible (h1 dead)

        // L3: 256 -> 64. wave: col-tile t5=wave>>1, K-half sh=wave&1;
        // reads ldsH (h2), partial sums -> pacc f32 [2][64][64] in ldsC
        {
            floatx4 zero = {0.f, 0.f, 0.f, 0.f};
            floatx4 acc5[4];
#pragma unroll
            for (int rt = 0; rt < 4; rt++) acc5[rt] = zero;
            int t5 = wave >> 1, sh = wave & 1;
#pragma unroll
            for (int u = 0; u < 4; u++) {
                int s = sh * 4 + u;
                short8 bf = *(const short8*)&w5p[((t5 * 8 + s) * 64 + lane) * 8];
#pragma unroll
                for (int rt = 0; rt < 4; rt++) {
                    short8 a = *(const short8*)&ldsH[(rt * 16 + n16) * H1S + s * 32 + q * 8];
                    acc5[rt] = MFMA_BF16(a, bf, acc5[rt], 0, 0, 0);
                }
            }
            float* pacc = (float*)ldsC;   // h1 dead
#pragma unroll
            for (int rt = 0; rt < 4; rt++)
#pragma unroll
                for (int r = 0; r < 4; r++)
                    pacc[(sh * 64 + rt * 16 + q * 4 + r) * 64 + t5 * 16 + n16] = acc5[rt][r];
        }
        __syncthreads();   // B4: pacc visible (all h2 reads done)

        // h3 = leaky(sum + b5): reads pacc (ldsC), writes h3 -> ldsH (H3S)
        {
            const float* pacc = (const float*)ldsC;
            for (int idx = tid; idx < 4096; idx += 512) {
                int row = idx >> 6, col = idx & 63;
                float v = pacc[row * 64 + col] + pacc[(64 + row) * 64 + col];
                ldsH[row * H3S + col] = f2bf(leaky(v + b5[col]));
            }
        }
        __syncthreads();   // B5: h3 visible (pacc dead)

        // L4: 64 -> 16(14). wave: k-step s=wave&1, row-tile rq=wave>>1 (0..3);
        // reads ldsH (h3), partials -> pacc2 f32 [2][64][16] in ldsC
        {
            floatx4 zero = {0.f, 0.f, 0.f, 0.f};
            floatx4 acc = zero;
            int s = wave & 1, rq = wave >> 1;
            short8 bf = *(const short8*)&w6p[(s * 64 + lane) * 8];
            short8 a = *(const short8*)&ldsH[(rq * 16 + n16) * H3S + s * 32 + q * 8];
            acc = MFMA_BF16(a, bf, acc, 0, 0, 0);
            float* pacc2 = (float*)ldsC;   // pacc dead
#pragma unroll
            for (int r = 0; r < 4; r++)
                pacc2[(s * 64 + rq * 16 + q * 4 + r) * 16 + n16] = acc[r];
        }
        __syncthreads();   // B6: pacc2 visible
        {
            const float* pacc2 = (const float*)ldsC;
            for (int idx = tid; idx < 1024; idx += 512) {
                int r = idx >> 4, c = idx & 15;
                float v = pacc2[idx] + pacc2[1024 + idx];
                if (c < 14) ez_out[(row0 + r) * 14 + c] = v + b6[c];
            }
        }
    } else {
        // ---------------- process model path (64 rows = 2 batches) ----------------
        const u16* w1p  = Pk + PW1;
        const u16* w3p  = Pk + PW3;
        const u16* wm2p = Pk + PWM2;
        const int bb   = blockIdx.x - 32;   // 0..1023
        const int row0 = bb * 64;

        // stage x (f32 -> bf16), zero-pad 140 -> 160 cols, into ldsH (stride XS)
        for (int idx = tid; idx < 64 * 42; idx += 512) {
            int r = idx / 42, c4 = idx - r * 42;
            float4 v = {0.f, 0.f, 0.f, 0.f};
            if (c4 < 35) v = *(const float4*)&Xg[(row0 + r) * 140 + c4 * 4];
            ushort4 pk;
            pk.x = f2bf(v.x); pk.y = f2bf(v.y); pk.z = f2bf(v.z); pk.w = f2bf(v.w);
            *(ushort4*)&ldsH[r * XS + c4 * 4] = pk;
        }
        __syncthreads();   // B1: stage visible

        // L1: [64x160] @ [160x256]; reads ldsH, publishes h1 -> ldsC
        {
            floatx4 zero = {0.f, 0.f, 0.f, 0.f};
            floatx4 acc1[4][2];
#pragma unroll
            for (int rt = 0; rt < 4; rt++)
#pragma unroll
                for (int ct = 0; ct < 2; ct++) acc1[rt][ct] = zero;
#pragma unroll
            for (int s = 0; s < 5; s++) {
                short8 a[4];
#pragma unroll
                for (int rt = 0; rt < 4; rt++)
                    a[rt] = *(const short8*)&ldsH[(rt * 16 + n16) * XS + s * 32 + q * 8];
#pragma unroll
                for (int ct = 0; ct < 2; ct++) {
                    int t = wave * 2 + ct;
                    short8 bf = *(const short8*)&w1p[((t * 5 + s) * 64 + lane) * 8];
#pragma unroll
                    for (int rt = 0; rt < 4; rt++)
                        acc1[rt][ct] = MFMA_BF16(a[rt], bf, acc1[rt][ct], 0, 0, 0);
                }
            }
#pragma unroll
            for (int ct = 0; ct < 2; ct++) {
                int col = (wave * 2 + ct) * 16 + n16;
                float bias = b1[col];
#pragma unroll
                for (int rt = 0; rt < 4; rt++)
#pragma unroll
                    for (int r = 0; r < 4; r++)
                        ldsC[(rt * 16 + q * 4 + r) * H1S + col] = f2bf(leaky(acc1[rt][ct][r] + bias));
            }
        }
        __syncthreads();   // B2: h1 visible (and all stage reads done)

        // L2 in 2 x 256-col chunks (h1 in ldsC stays live; h2 chunks -> ldsH)
        // + L3 partial per chunk
        floatx4 acc3[2];
        {
            floatx4 zero = {0.f, 0.f, 0.f, 0.f};
            acc3[0] = zero; acc3[1] = zero;
        }
        const int h = wave >> 2;       // row-half for L3
        const int pg = wave & 3;       // k-step group for L3
#pragma unroll
        for (int c = 0; c < 2; c++) {
            floatx4 zero = {0.f, 0.f, 0.f, 0.f};
            floatx4 acc[4][2];
#pragma unroll
            for (int rt = 0; rt < 4; rt++)
#pragma unroll
                for (int ct = 0; ct < 2; ct++) acc[rt][ct] = zero;
#pragma unroll
            for (int s = 0; s < 8; s++) {
                short8 a[4];
#pragma unroll
                for (int rt = 0; rt < 4; rt++)
                    a[rt] = *(const short8*)&ldsC[(rt * 16 + n16) * H1S + s * 32 + q * 8];
#pragma unroll
                for (int ct = 0; ct < 2; ct++) {
                    int tg = c * 16 + wave * 2 + ct;
                    short8 bf = *(const short8*)&w3p[((tg * 8 + s) * 64 + lane) * 8];
#pragma unroll
                    for (int rt = 0; rt < 4; rt++)
                        acc[rt][ct] = MFMA_BF16(a[rt], bf, acc[rt][ct], 0, 0, 0);
                }
            }
#pragma unroll
            for (int ct = 0; ct < 2; ct++) {
                int cl = (wave * 2 + ct) * 16 + n16;
                float bias = b3[c * 256 + cl];
#pragma unroll
                for (int rt = 0; rt < 4; rt++)
#pragma unroll
                    for (int r = 0; r < 4; r++)
                        ldsH[(rt * 16 + q * 4 + r) * H1S + cl] = f2bf(leaky(acc[rt][ct][r] + bias));
            }
            __syncthreads();   // h2 chunk visible
            // L3 partial: this chunk's 8 k-steps; wave covers 2 on its row-half
#pragma unroll
            for (int uu = 0; uu < 2; uu++) {
                int sgl = pg * 2 + uu;              // k-step within chunk, 0..7
                short8 bf = *(const short8*)&wm2p[((c * 8 + sgl) * 64 + lane) * 8];
#pragma unroll
                for (int rt = 0; rt < 2; rt++) {
                    short8 a = *(const short8*)&ldsH[(h * 32 + rt * 16 + n16) * H1S + sgl * 32 + q * 8];
                    acc3[rt] = MFMA_BF16(a, bf, acc3[rt], 0, 0, 0);
                }
            }
            __syncthreads();   // chunk consumed (ldsH reusable)
        }

        // reduce 4 k-partials per row via pacc f32 [4][64][16] in ldsH (h2 dead)
        {
            float* pacc = (float*)ldsH;
#pragma unroll
            for (int rt = 0; rt < 2; rt++)
#pragma unroll
                for (int r = 0; r < 4; r++)
                    pacc[(pg * 64 + h * 32 + rt * 16 + q * 4 + r) * 16 + n16] = acc3[rt][r];
        }
        __syncthreads();
        {
            const float* pacc = (const float*)ldsH;
            for (int idx = tid; idx < 1024; idx += 512) {
                int r = idx >> 4, c = idx & 15;
                float v = pacc[idx] + pacc[1024 + idx] + pacc[2048 + idx] + pacc[3072 + idx];
                if (c < 14) sp_ws[(row0 + r) * 14 + c] = v + bm2[c];
            }
        }
    }
}

// ===========================================================================
// EnKF tail, v3: barrier-free. One WAVE per batch (wave-internal LDS is
// in-order — precedent: the original session's single-wave no-barrier GJ
// passed), 4 batches per 256-thread block -> 512 blocks. ~35 barriers -> 0.
// LDS 22KB/block -> 7 blocks/CU = 28 waves/CU.
// Algebraic cut: R diagonal => K = S(S+R)^-1 = I - R*(S+R)^-1, so no M
// array and no K matmul; gain_ei = d_ei - rrv_i * sum_j Ginv[i][j] d_ej.
// ===========================================================================
__global__ __launch_bounds__(256) void enkf_tail(
    const float* __restrict__ sp_all,
    const float* __restrict__ on_w1, const float* __restrict__ on_b1,
    const float* __restrict__ on_w2, const float* __restrict__ on_b2,
    float* out)
{
    __shared__ float spv[4][32][14];
    __shared__ float ezv[4][32][14];
    __shared__ float smv[4][14], zzv[4][14], rrv[4][14];
    __shared__ float G[4][14][28];
    __shared__ float fac[4][14];
    __shared__ float hbuf[4][32];

    const int tid = threadIdx.x;
    const int w = tid >> 6;        // wave id = batch slot
    const int l = tid & 63;
    const int b = blockIdx.x * 4 + w;

    float* sp = &spv[w][0][0];
    float* ez = &ezv[w][0][0];

    for (int idx = l; idx < 448; idx += 64) sp[idx] = sp_all[b * 448 + idx];
    {
        const float* ezsrc = out + O4 + (b & 63) * 448;
        for (int idx = l; idx < 448; idx += 64) ez[idx] = ezsrc[idx];
    }
    // No barriers below: all LDS state is wave-private, wave ops in-order.

    // means: lanes 0..13 sp-mean, lanes 32..45 ez-mean
    if (l < 14) {
        float s = 0.f;
        for (int e = 0; e < 32; e++) s += spv[w][e][l];
        smv[w][l] = s * (1.f / 32.f);
    } else if (l >= 32 && l < 46) {
        int c = l - 32;
        float s = 0.f;
        for (int e = 0; e < 32; e++) s += ezv[w][e][c];
        zzv[w][c] = s * (1.f / 32.f);
    }

    // R-MLP: relu(z @ w1 + b1) @ w2 + b2 -> rrv
    if (l < 32) {
        float t = on_b1[l];
        for (int k = 0; k < 14; k++) t += zzv[w][k] * on_w1[k * 32 + l];
        hbuf[w][l] = t > 0.f ? t : 0.f;
    }
    if (l < 14) {
        float t = on_b2[l];
        for (int k = 0; k < 32; k++) t += hbuf[w][k] * on_w2[k * 14 + l];
        t += 0.001f;
        rrv[w][l] = t * t + 0.038729833f;
    }

    // augmented [cov/31 + diag(rrv) | I] built directly (no M array)
    for (int idx = l; idx < 196; idx += 64) {
        int i = idx / 14, j = idx - i * 14;
        float mi = smv[w][i], mj = smv[w][j];
        float s = 0.f;
        for (int e = 0; e < 32; e++) s += (spv[w][e][i] - mi) * (spv[w][e][j] - mj);
        s *= (1.f / 31.f);
        G[w][i][j] = s + (i == j ? rrv[w][i] : 0.f);
        G[w][i][14 + j] = (i == j) ? 1.f : 0.f;
    }

    // Gauss-Jordan (SPD, no pivoting), wave-private, barrier-free
    for (int c = 0; c < 14; c++) {
        float pinv = 1.f / G[w][c][c];       // read precedes row-c write (in-order)
        if (l < 28) G[w][c][l] *= pinv;
        if (l < 14 && l != c) fac[w][l] = G[w][l][c];
        for (int idx = l; idx < 392; idx += 64) {
            int i = idx / 28, j = idx - i * 28;
            if (i != c) G[w][i][j] -= fac[w][i] * G[w][c][j];
        }
    }

    // gain + outputs: K = I - diag(rrv) * Ginv
    for (int idx = l; idx < 448; idx += 64) {
        int e = idx / 14, i = idx - e * 14;
        float acc = 0.f;
        for (int j = 0; j < 14; j++)
            acc += G[w][i][14 + j] * (ezv[w][e][j] - spv[w][e][j]);
        float di = ezv[w][e][i] - spv[w][e][i];
        float g = di - rrv[w][i] * acc;
        out[b * 448 + idx] = spv[w][e][i] + g;      // state_corrected
        out[O4 + b * 448 + idx] = ezv[w][e][i];     // ensemble_z
    }
    if (l < 14) {
        float acc = 0.f;
        for (int j = 0; j < 14; j++)
            acc += G[w][l][14 + j] * (zzv[w][j] - smv[w][j]);
        float di = zzv[w][l] - smv[w][l];
        float g = di - rrv[w][l] * acc;
        out[O1 + b * 14 + l] = smv[w][l] + g;       // corrected mean (linearity)
        out[O2 + b * 14 + l] = smv[w][l];           // state_m
        out[O3 + b * 14 + l] = zzv[w][l];           // z
    }
}

// ===========================================================================
extern "C" void kernel_launch(void* const* d_in, const int* in_sizes, int n_in,
                              void* d_out, int out_size, void* d_ws, size_t ws_size,
                              hipStream_t stream) {
    (void)in_sizes; (void)n_in; (void)out_size; (void)ws_size;

    const float* raw_obs    = (const float*)d_in[0];
    const float* state_prev = (const float*)d_in[1];
    const float* pm_w1  = (const float*)d_in[2];
    const float* pm_b1  = (const float*)d_in[3];
    const float* pm_w3  = (const float*)d_in[4];
    const float* pm_b3  = (const float*)d_in[5];
    const float* pm_wm2 = (const float*)d_in[6];
    const float* pm_bm2 = (const float*)d_in[7];
    const float* sm_w2  = (const float*)d_in[8];
    const float* sm_b2  = (const float*)d_in[9];
    const float* sm_w3  = (const float*)d_in[10];
    const float* sm_b3  = (const float*)d_in[11];
    const float* sm_w5  = (const float*)d_in[12];
    const float* sm_b5  = (const float*)d_in[13];
    const float* sm_w6  = (const float*)d_in[14];
    const float* sm_b6  = (const float*)d_in[15];
    const float* on_w1  = (const float*)d_in[16];
    const float* on_b1  = (const float*)d_in[17];
    const float* on_w2  = (const float*)d_in[18];
    const float* on_b2  = (const float*)d_in[19];

    float* out = (float*)d_out;
    u16* P = (u16*)d_ws;
    float* sp_ws = (float*)((char*)d_ws + WS_NEEDED);

    PackArgs pa;
    pa.seg[0] = { pm_w1,  140, 256, 5,  PW1,  40960  };
    pa.seg[1] = { pm_w3,  256, 512, 8,  PW3,  131072 };
    pa.seg[2] = { pm_wm2, 512, 14,  16, PWM2, 8192   };
    pa.seg[3] = { sm_w2,  220, 256, 7,  PSW2, 57344  };
    pa.seg[4] = { sm_w3,  256, 256, 8,  PSW3, 65536  };
    pa.seg[5] = { sm_w5,  256, 64,  8,  PSW5, 16384  };
    pa.seg[6] = { sm_w6,  64,  14,  2,  PSW6, 1024   };
    pack_all<<<(PTOTAL + 255) / 256, 256, 0, stream>>>(pa, P);

    merged_mlp<<<1056, 512, 0, stream>>>(raw_obs, state_prev, P,
                                         pm_b1, pm_b3, pm_bm2,
                                         sm_b2, sm_b3, sm_b5, sm_b6,
                                         out + O4, sp_ws);
    enkf_tail<<<512, 256, 0, stream>>>(sp_ws, on_w1, on_b1, on_w2, on_b2, out);
}